// Round 11
// baseline (91.546 us; speedup 1.0000x reference)
//
#include <hip/hip_runtime.h>

// MoE experts: transform W (page-streaming fp32 -> bf16 swizzled packets) -> route ->
// gather(bf16) -> grouped GEMM1+silu -> grouped GEMM2 (per-pair partials) -> combine.
// No memset, no atomics. GEMM staging is pure global_load_lds from L3-resident packets.
#define E_ 16
#define T_ 2048
#define H_ 1024
#define I_ 512
#define NPAIR 4096             // T*K token-expert pairs
#define BM 128
#define MAXTILE 48             // sum ceil(ne/BM) <= 32 + 16

typedef __bf16 bf16x8 __attribute__((ext_vector_type(8)));
typedef float  f32x4  __attribute__((ext_vector_type(4)));

static __device__ __forceinline__ unsigned short f2bf(float f) {
    __bf16 h = (__bf16)f;                       // RNE
    return __builtin_bit_cast(unsigned short, h);
}

static __device__ __forceinline__ uint4 pack8(const float* v) {
    union { unsigned short us[8]; uint4 u; } r;
    #pragma unroll
    for (int i = 0; i < 8; ++i) r.us[i] = f2bf(v[i]);
    return r.u;
}

// async global->LDS, 16B/lane; dest wave-uniform base + lane*16 (linear);
// source address is per-lane.
static __device__ __forceinline__ void gl_lds16(const void* g, void* l) {
    __builtin_amdgcn_global_load_lds(
        (const __attribute__((address_space(1))) unsigned int*)g,
        (__attribute__((address_space(3))) unsigned int*)l,
        16, 0, 0);
}

#define RAW_BARRIER_LGKM                                                \
    asm volatile("s_waitcnt lgkmcnt(0)" ::: "memory");                  \
    asm volatile("s_barrier" ::: "memory");

// ---------------- routing: stable counting sort + tile map + inverse -------
__global__ __launch_bounds__(256) void route_kernel(
    const float* __restrict__ tw, const int* __restrict__ ti,
    int* __restrict__ offs, int* __restrict__ tile_e, int* __restrict__ tile_r,
    int* __restrict__ pair_ts, float* __restrict__ pair_w, int* __restrict__ inv)
{
    __shared__ unsigned short hist[256][E_];
    __shared__ int ebase[E_];
    const int tid = threadIdx.x;

    int e_loc[16];
    unsigned short h[E_];
    for (int e = 0; e < E_; ++e) h[e] = 0;
    for (int i = 0; i < 16; ++i) {
        int p = tid * 16 + i;
        int e = ti[p];
        e_loc[i] = e;
        h[e]++;
    }
    for (int e = 0; e < E_; ++e) hist[tid][e] = h[e];
    __syncthreads();

    if (tid < E_) {
        int e = tid, run = 0;
        for (int t = 0; t < 256; ++t) {
            unsigned short c = hist[t][e];
            hist[t][e] = (unsigned short)run;
            run += c;
        }
        ebase[e] = run;
    }
    __syncthreads();
    if (tid == 0) {
        int run = 0, nt = 0;
        for (int e = 0; e < E_; ++e) {
            int c = ebase[e];
            offs[e] = run; ebase[e] = run;
            for (int r = 0; r < c; r += BM) { tile_e[nt] = e; tile_r[nt] = r; ++nt; }
            run += c;
        }
        offs[E_] = run;
        for (; nt < MAXTILE; ++nt) tile_e[nt] = -1;
    }
    __syncthreads();

    int cur[E_];
    for (int e = 0; e < E_; ++e) cur[e] = ebase[e] + hist[tid][e];
    for (int i = 0; i < 16; ++i) {
        int p = tid * 16 + i;
        int e = e_loc[i];
        int pos = cur[e]++;
        pair_ts[pos] = p;          // t = p>>1
        pair_w[pos]  = tw[p];
        inv[p]       = pos;
    }
}

// ---------------- gather: Ag[q][:] = bf16(X[token(q)][:]) ------------------
__global__ __launch_bounds__(256) void gather_kernel(
    const float* __restrict__ X, const int* __restrict__ pair_ts,
    unsigned short* __restrict__ Ag)
{
    const int q = blockIdx.x;
    const int t = pair_ts[q] >> 1;
    const int c = threadIdx.x * 4;
    const float4 x = *(const float4*)&X[(size_t)t * H_ + c];
    ushort4 b; b.x = f2bf(x.x); b.y = f2bf(x.y); b.z = f2bf(x.z); b.w = f2bf(x.w);
    *(ushort4*)&Ag[(size_t)q * H_ + c] = b;
}

// ---------------- W repack v2: page-streaming fp32 -> bf16 packets ---------
// Packet(e,colblk,ks) = 64 rows x 8 granules(16B): granule p of row bn holds
// k = ks*64 + (p^(bn&7))*8 + j of col(bn). Contiguous 8KB per packet.
// Block = (matrix, e, ks, col-half): reads 64 rows x 512 CONTIGUOUS floats
// (2KB/row; sibling half-block covers the other 2KB of each 4KB page, adjacent
// in dispatch order). 4 chunks of 128 cols, reg-staged double buffer, raw
// lgkm-only barriers so global loads stay in flight.
// Grid: 512 W1 blocks (e*16ks*2half) + 256 W2 blocks (e*8ks*2half) = 768.
#define TLOADC(R, CH)                                                                  \
    _Pragma("unroll")                                                                  \
    for (int i = 0; i < 8; ++i)                                                        \
        R[i] = *(const float4*)(src + (size_t)((t >> 5) + i * 8) * 1024 + (CH) * 128 + (t & 31) * 4);

#define TWRC(B, R)                                                                     \
    _Pragma("unroll")                                                                  \
    for (int i = 0; i < 8; ++i) {                                                      \
        ushort4 u_;                                                                    \
        u_.x = f2bf(R[i].x); u_.y = f2bf(R[i].y); u_.z = f2bf(R[i].z); u_.w = f2bf(R[i].w); \
        *(ushort4*)&tile[B][(t >> 5) + i * 8][(t & 31) * 4] = u_;                      \
    }

#define TPACKC(CH, B)                                                                  \
    {                                                                                  \
        const int cl = (CH) * 128 + (t >> 1);                                          \
        int bn_; size_t dstoff;                                                        \
        if (isW1) {                                                                    \
            int cb = cl >> 5, grp = (cl >> 4) & 1, sub = cl & 15;                      \
            bn_ = grp * 32 + half * 16 + sub;                                          \
            dstoff = ((size_t)((e * 16 + cb) * 16 + ks)) * 4096;                       \
        } else {                                                                       \
            int gcol = half * 512 + cl;                                                \
            int hb = gcol >> 6; bn_ = gcol & 63;                                       \
            dstoff = ((size_t)((e * 16 + hb) * 8 + ks)) * 4096;                        \
        }                                                                              \
        unsigned short* dp = dstO + dstoff + bn_ * 64;                                 \
        _Pragma("unroll")                                                              \
        for (int u = 0; u < 4; ++u) {                                                  \
            int p = (t & 1) * 4 + u;                                                   \
            int kl = (p ^ (bn_ & 7)) * 8;                                              \
            union { unsigned short us[8]; uint4 q; } g_;                               \
            _Pragma("unroll")                                                          \
            for (int j = 0; j < 8; ++j) g_.us[j] = tile[B][kl + j][t >> 1];            \
            *(uint4*)&dp[p * 8] = g_.q;                                                \
        }                                                                              \
    }

__global__ __launch_bounds__(256, 4) void transform_kernel(
    const float* __restrict__ W1, const float* __restrict__ W2,
    unsigned short* __restrict__ W1t, unsigned short* __restrict__ W2t)
{
    __shared__ unsigned short tile[2][64][140];   // 280B row: pack reads <=2-way
    const int t   = threadIdx.x;
    const int bid = blockIdx.x;

    const float* src;
    unsigned short* dstO;
    int isW1, half, ks, e;
    if (bid < 512) {                       // W1: half(2) x ks(16) x e(16)
        isW1 = 1;
        half = bid & 1; ks = (bid >> 1) & 15; e = bid >> 5;
        src  = W1 + (size_t)e * (H_ * 2 * I_) + (size_t)(ks * 64) * (2 * I_) + half * 512;
        dstO = W1t;
    } else {                               // W2: half(2) x ks(8) x e(16)
        int b2 = bid - 512;
        isW1 = 0;
        half = b2 & 1; ks = (b2 >> 1) & 7; e = b2 >> 4;
        src  = W2 + (size_t)e * (I_ * H_) + (size_t)(ks * 64) * H_ + half * 512;
        dstO = W2t;
    }

    float4 r0[8], r1[8];
    TLOADC(r0, 0)
    TWRC(0, r0)
    TLOADC(r1, 1)
    RAW_BARRIER_LGKM
    // c = 0
    TPACKC(0, 0)
    TWRC(1, r1)
    TLOADC(r0, 2)
    RAW_BARRIER_LGKM
    // c = 1
    TPACKC(1, 1)
    TWRC(0, r0)
    TLOADC(r1, 3)
    RAW_BARRIER_LGKM
    // c = 2
    TPACKC(2, 0)
    TWRC(1, r1)
    RAW_BARRIER_LGKM
    // c = 3
    TPACKC(3, 1)
}

// ---------------- shared GEMM machinery ------------------------------------
// 4 waves (2x2), wave tile 64x32, block 128x64, BK=64.
// XOR-swizzled bf16 LDS: 16B granule g of row r holds k-granule g^(r&7).
#define MFMA_TILE(AS, BS)                                                              \
    _Pragma("unroll")                                                                  \
    for (int kkj = 0; kkj < 2; ++kkj) {                                                \
        const int j0 = kkj * 4;                                                        \
        bf16x8 af[4], bfr[2];                                                          \
        _Pragma("unroll")                                                              \
        for (int m = 0; m < 4; ++m)                                                    \
            af[m] = *(const bf16x8*)&AS[wm * 64 + m * 16 + lrow][((j0 + lk) ^ (lrow & 7)) * 8]; \
        _Pragma("unroll")                                                              \
        for (int n = 0; n < 2; ++n)                                                    \
            bfr[n] = *(const bf16x8*)&BS[wn * 32 + n * 16 + lrow][((j0 + lk) ^ (lrow & 7)) * 8]; \
        _Pragma("unroll")                                                              \
        for (int m = 0; m < 4; ++m)                                                    \
            _Pragma("unroll")                                                          \
            for (int n = 0; n < 2; ++n)                                                \
                acc[m][n] = __builtin_amdgcn_mfma_f32_16x16x32_bf16(af[m], bfr[n], acc[m][n], 0, 0, 0); \
    }

#define STAGE_A(BUF, KB)                                                               \
    _Pragma("unroll")                                                                  \
    for (int i = 0; i < 4; ++i) gl_lds16(asrc[i] + (KB), &As[BUF][w * 32 + i * 8][0]);

#define STAGE_B(BUF, KS)                                                               \
    _Pragma("unroll")                                                                  \
    for (int i = 0; i < 2; ++i)                                                        \
        gl_lds16(bsrcB + (size_t)(KS) * 4096 + i * 512,                                \
                 &Bs[BUF][0][0] + w * 1024 + i * 512);

#define K_PIPE(NT)                                                                     \
    STAGE_A(0, 0)                                                                      \
    STAGE_B(0, 0)                                                                      \
    __syncthreads();                                                                   \
    int cur = 0;                                                                       \
    _Pragma("unroll")                                                                  \
    for (int kt = 0; kt < (NT); ++kt) {                                                \
        int nxt = cur ^ 1;                                                             \
        if (kt + 1 < (NT)) { STAGE_A(nxt, (kt + 1) * 64) STAGE_B(nxt, kt + 1) }        \
        __builtin_amdgcn_s_setprio(1);                                                 \
        MFMA_TILE(As[cur], Bs[cur])                                                    \
        __builtin_amdgcn_s_setprio(0);                                                 \
        __syncthreads();                                                               \
        cur = nxt;                                                                     \
    }

// ---------------- grouped GEMM1 + fused silu-gate --------------------------
__global__ __launch_bounds__(256, 3) void gemm1_kernel(
    const unsigned short* __restrict__ Ag, const unsigned short* __restrict__ W1t,
    const int* __restrict__ offs, const int* __restrict__ tile_e,
    const int* __restrict__ tile_r, unsigned short* __restrict__ act)
{
    const int e = tile_e[blockIdx.y];
    if (e < 0) return;
    const int rbeg = offs[e], rend = offs[e + 1];
    const int ne   = rend - rbeg;
    const int row0 = tile_r[blockIdx.y];
    const int cb   = blockIdx.x;             // 0..15
    const int c0   = cb * 32;                // act col block

    __shared__ unsigned short As[2][128][64];   // 32 KB
    __shared__ unsigned short Bs[2][64][64];    // 16 KB

    const int tid  = threadIdx.x;
    const int lane = tid & 63;
    const int w    = tid >> 6;        // 0..3
    const int wm   = w >> 1, wn = w & 1;
    const int lrow = lane & 15;
    const int lk   = lane >> 4;

    const int r8 = lane >> 3, gr = lane & 7;
    const unsigned short* asrc[4];
    #pragma unroll
    for (int i = 0; i < 4; ++i) {
        int q = rbeg + row0 + w * 32 + i * 8 + r8;
        if (q > rend - 1) q = rend - 1;
        asrc[i] = Ag + (size_t)q * H_ + (gr ^ r8) * 8;
    }

    const unsigned short* bsrcB =
        W1t + ((size_t)(e * 16 + cb) * 16) * 4096 + w * 1024 + lane * 8;

    f32x4 acc[4][2];
    #pragma unroll
    for (int m = 0; m < 4; ++m)
        #pragma unroll
        for (int n = 0; n < 2; ++n)
            acc[m][n] = f32x4{0.f, 0.f, 0.f, 0.f};

    K_PIPE(16)

    for (int m = 0; m < 4; ++m) {
        #pragma unroll
        for (int reg = 0; reg < 4; ++reg) {
            int rloc = wm * 64 + m * 16 + lk * 4 + reg;
            if (row0 + rloc < ne) {
                int q = rbeg + row0 + rloc;
                float g = acc[m][0][reg], u = acc[m][1][reg];
                float a = g / (1.f + __expf(-g)) * u;
                act[(size_t)q * I_ + c0 + wn * 16 + lrow] = f2bf(a);
            }
        }
    }
}

// ---------------- grouped GEMM2 -> per-pair partials (no atomics) ----------
__global__ __launch_bounds__(256, 3) void gemm2_kernel(
    const unsigned short* __restrict__ Agact, const unsigned short* __restrict__ W2t,
    const int* __restrict__ offs, const int* __restrict__ tile_e,
    const int* __restrict__ tile_r, const float* __restrict__ pair_w,
    float* __restrict__ C2)
{
    const int e = tile_e[blockIdx.y];
    if (e < 0) return;
    const int rbeg = offs[e], rend = offs[e + 1];
    const int ne   = rend - rbeg;
    const int row0 = tile_r[blockIdx.y];
    const int hb   = blockIdx.x;             // 0..15
    const int c0   = hb * 64;

    __shared__ unsigned short As[2][128][64];
    __shared__ unsigned short Bs[2][64][64];

    const int tid  = threadIdx.x;
    const int lane = tid & 63;
    const int w    = tid >> 6;
    const int wm   = w >> 1, wn = w & 1;
    const int lrow = lane & 15;
    const int lk   = lane >> 4;

    const int r8 = lane >> 3, gr = lane & 7;
    const unsigned short* asrc[4];
    #pragma unroll
    for (int i = 0; i < 4; ++i) {
        int q = rbeg + row0 + w * 32 + i * 8 + r8;
        if (q > rend - 1) q = rend - 1;
        asrc[i] = Agact + (size_t)q * I_ + (gr ^ r8) * 8;
    }

    const unsigned short* bsrcB =
        W2t + ((size_t)(e * 16 + hb) * 8) * 4096 + w * 1024 + lane * 8;

    f32x4 acc[4][2];
    #pragma unroll
    for (int m = 0; m < 4; ++m)
        #pragma unroll
        for (int n = 0; n < 2; ++n)
            acc[m][n] = f32x4{0.f, 0.f, 0.f, 0.f};

    K_PIPE(8)

    for (int m = 0; m < 4; ++m) {
        #pragma unroll
        for (int reg = 0; reg < 4; ++reg) {
            int rloc = wm * 64 + m * 16 + lk * 4 + reg;
            if (row0 + rloc < ne) {
                int q   = rbeg + row0 + rloc;
                float wt = pair_w[q];
                #pragma unroll
                for (int n = 0; n < 2; ++n) {
                    int cg = c0 + wn * 32 + n * 16 + lrow;
                    C2[(size_t)q * H_ + cg] = wt * acc[m][n][reg];
                }
            }
        }
    }
}

// ---------------- combine: out[t] = C2[inv[2t]] + C2[inv[2t+1]] ------------
__global__ __launch_bounds__(256) void combine_kernel(
    const float* __restrict__ C2, const int* __restrict__ inv,
    float* __restrict__ out)
{
    const int t = blockIdx.x;
    const int c = threadIdx.x * 4;
    const int q0 = inv[2 * t], q1 = inv[2 * t + 1];
    const float4 a = *(const float4*)&C2[(size_t)q0 * H_ + c];
    const float4 b = *(const float4*)&C2[(size_t)q1 * H_ + c];
    float4 o;
    o.x = a.x + b.x; o.y = a.y + b.y; o.z = a.z + b.z; o.w = a.w + b.w;
    *(float4*)&out[(size_t)t * H_ + c] = o;
}

extern "C" void kernel_launch(void* const* d_in, const int* in_sizes, int n_in,
                              void* d_out, int out_size, void* d_ws, size_t ws_size,
                              hipStream_t stream)
{
    const float* X  = (const float*)d_in[0];   // [T,H]
    const float* tw = (const float*)d_in[1];   // [T,K]
    const int*   ti = (const int*)d_in[2];     // [T,K]
    const float* W1 = (const float*)d_in[3];   // [E,H,2I]
    const float* W2 = (const float*)d_in[4];   // [E,I,H]
    float* out = (float*)d_out;                // [T,H] fp32

    char* ws = (char*)d_ws;
    int*   offs    = (int*)(ws);               // 17 ints
    int*   tile_e  = (int*)(ws + 128);
    int*   tile_r  = (int*)(ws + 320);
    int*   pair_ts = (int*)(ws + 1024);
    float* pair_w  = (float*)(ws + 1024 + NPAIR * 4);
    int*   inv     = (int*)(ws + 1024 + NPAIR * 8);
    unsigned short* Ag  = (unsigned short*)(ws + (size_t)(1u << 16));            // 8 MiB
    unsigned short* act = (unsigned short*)(ws + (size_t)(1u << 16) + 8388608);  // 4 MiB
    unsigned short* W1t = (unsigned short*)(ws + (size_t)(1u << 16) + 12582912); // 32 MiB
    unsigned short* W2t = (unsigned short*)(ws + (size_t)(1u << 16) + 46137344); // 16 MiB
    float*          C2  = (float*)(ws + (size_t)(1u << 16) + 62914560);          // 16 MiB

    transform_kernel<<<768, 256, 0, stream>>>(W1, W2, W1t, W2t);

    route_kernel<<<1, 256, 0, stream>>>(tw, ti, offs, tile_e, tile_r, pair_ts, pair_w, inv);

    gather_kernel<<<NPAIR, 256, 0, stream>>>(X, pair_ts, Ag);

    gemm1_kernel<<<dim3(16, MAXTILE), 256, 0, stream>>>(Ag, W1t, offs, tile_e, tile_r, act);

    gemm2_kernel<<<dim3(16, MAXTILE), 256, 0, stream>>>(act, W2t, offs, tile_e, tile_r, pair_w, C2);

    combine_kernel<<<T_, 256, 0, stream>>>(C2, inv, out);
}

// Round 12
// 89.744 us; speedup vs baseline: 1.0201x; 1.0201x over previous
//
#include <hip/hip_runtime.h>

// MoE experts: transform W (fp32 -> bf16 swizzled packets, max-TLP single-phase) ->
// route -> gather(bf16) -> grouped GEMM1+silu -> grouped GEMM2 (per-pair partials) -> combine.
// No memset, no atomics. GEMM staging is pure global_load_lds from L3-resident packets.
#define E_ 16
#define T_ 2048
#define H_ 1024
#define I_ 512
#define NPAIR 4096             // T*K token-expert pairs
#define BM 128
#define MAXTILE 48             // sum ceil(ne/BM) <= 32 + 16

typedef __bf16 bf16x8 __attribute__((ext_vector_type(8)));
typedef float  f32x4  __attribute__((ext_vector_type(4)));

static __device__ __forceinline__ unsigned short f2bf(float f) {
    __bf16 h = (__bf16)f;                       // RNE
    return __builtin_bit_cast(unsigned short, h);
}

// async global->LDS, 16B/lane; dest wave-uniform base + lane*16 (linear);
// source address is per-lane.
static __device__ __forceinline__ void gl_lds16(const void* g, void* l) {
    __builtin_amdgcn_global_load_lds(
        (const __attribute__((address_space(1))) unsigned int*)g,
        (__attribute__((address_space(3))) unsigned int*)l,
        16, 0, 0);
}

// ---------------- routing: stable counting sort + tile map + inverse -------
__global__ __launch_bounds__(256) void route_kernel(
    const float* __restrict__ tw, const int* __restrict__ ti,
    int* __restrict__ offs, int* __restrict__ tile_e, int* __restrict__ tile_r,
    int* __restrict__ pair_ts, float* __restrict__ pair_w, int* __restrict__ inv)
{
    __shared__ unsigned short hist[256][E_];
    __shared__ int ebase[E_];
    const int tid = threadIdx.x;

    int e_loc[16];
    unsigned short h[E_];
    for (int e = 0; e < E_; ++e) h[e] = 0;
    for (int i = 0; i < 16; ++i) {
        int p = tid * 16 + i;
        int e = ti[p];
        e_loc[i] = e;
        h[e]++;
    }
    for (int e = 0; e < E_; ++e) hist[tid][e] = h[e];
    __syncthreads();

    if (tid < E_) {
        int e = tid, run = 0;
        for (int t = 0; t < 256; ++t) {
            unsigned short c = hist[t][e];
            hist[t][e] = (unsigned short)run;
            run += c;
        }
        ebase[e] = run;
    }
    __syncthreads();
    if (tid == 0) {
        int run = 0, nt = 0;
        for (int e = 0; e < E_; ++e) {
            int c = ebase[e];
            offs[e] = run; ebase[e] = run;
            for (int r = 0; r < c; r += BM) { tile_e[nt] = e; tile_r[nt] = r; ++nt; }
            run += c;
        }
        offs[E_] = run;
        for (; nt < MAXTILE; ++nt) tile_e[nt] = -1;
    }
    __syncthreads();

    int cur[E_];
    for (int e = 0; e < E_; ++e) cur[e] = ebase[e] + hist[tid][e];
    for (int i = 0; i < 16; ++i) {
        int p = tid * 16 + i;
        int e = e_loc[i];
        int pos = cur[e]++;
        pair_ts[pos] = p;          // t = p>>1
        pair_w[pos]  = tw[p];
        inv[p]       = pos;
    }
}

// ---------------- gather: Ag[q][:] = bf16(X[token(q)][:]) ------------------
__global__ __launch_bounds__(256) void gather_kernel(
    const float* __restrict__ X, const int* __restrict__ pair_ts,
    unsigned short* __restrict__ Ag)
{
    const int q = blockIdx.x;
    const int t = pair_ts[q] >> 1;
    const int c = threadIdx.x * 4;
    const float4 x = *(const float4*)&X[(size_t)t * H_ + c];
    ushort4 b; b.x = f2bf(x.x); b.y = f2bf(x.y); b.z = f2bf(x.z); b.w = f2bf(x.w);
    *(ushort4*)&Ag[(size_t)q * H_ + c] = b;
}

// ---------------- W repack v3: max-TLP single-phase ------------------------
// Packet(e,colblk,ks) = 64 rows x 8 granules(16B): granule p of row bn holds
// k = ks*64 + (p^(bn&7))*8 + j of col(bn). Contiguous 8KB per packet.
// Block = one 64-row x 128-col chunk (32KB read, 16KB write). 3072 blocks,
// 18KB LDS -> 8 blocks/CU, ~100% occupancy; latency hidden by cross-block TLP
// (no intra-block pipeline, single barrier).
// Grid: W1 ch(8) x ks(16) x e(16) = 2048, then W2 ch(8) x ks(8) x e(16) = 1024.
__global__ __launch_bounds__(256) void transform_kernel(
    const float* __restrict__ W1, const float* __restrict__ W2,
    unsigned short* __restrict__ W1t, unsigned short* __restrict__ W2t)
{
    __shared__ unsigned short tile[64][140];   // 280B row stride: <=2-way everywhere
    const int t   = threadIdx.x;
    const int bid = blockIdx.x;

    const float* src;
    unsigned short* dstO;
    int isW1, ch, ks, e;
    if (bid < 2048) {                      // W1
        isW1 = 1;
        ch = bid & 7; ks = (bid >> 3) & 15; e = bid >> 7;
        src  = W1 + (size_t)e * (H_ * 2 * I_) + (size_t)(ks * 64) * 1024 + ch * 128;
        dstO = W1t;
    } else {                               // W2
        int b2 = bid - 2048;
        isW1 = 0;
        ch = b2 & 7; ks = (b2 >> 3) & 7; e = b2 >> 6;
        src  = W2 + (size_t)e * (I_ * H_) + (size_t)(ks * 64) * 1024 + ch * 128;
        dstO = W2t;
    }

    // load 64x128 fp32 chunk, convert, store bf16 tile (2-way max on LDS writes)
    const int r0 = t >> 5, c4 = (t & 31) * 4;
    #pragma unroll
    for (int i = 0; i < 8; ++i) {
        const float4 v = *(const float4*)(src + (size_t)(r0 + i * 8) * 1024 + c4);
        ushort4 u;
        u.x = f2bf(v.x); u.y = f2bf(v.y); u.z = f2bf(v.z); u.w = f2bf(v.w);
        *(ushort4*)&tile[r0 + i * 8][c4] = u;
    }
    __syncthreads();

    // pack: thread pair (2j,2j+1) emits the 8 granules of packet row bn(col j)
    const int cl = t >> 1;                 // 0..127 col within chunk
    const int c  = ch * 128 + cl;          // global col
    int bn_; size_t dstoff;
    if (isW1) {
        int half = c >> 9, cc = c & 511;
        int cb = cc >> 5, grp = (cc >> 4) & 1, sub = cc & 15;
        bn_ = grp * 32 + half * 16 + sub;
        dstoff = ((size_t)((e * 16 + cb) * 16 + ks)) * 4096;
    } else {
        int hb = c >> 6; bn_ = c & 63;
        dstoff = ((size_t)((e * 16 + hb) * 8 + ks)) * 4096;
    }
    unsigned short* dp = dstO + dstoff + bn_ * 64;
    #pragma unroll
    for (int u = 0; u < 4; ++u) {
        int p  = (t & 1) * 4 + u;
        int kl = (p ^ (bn_ & 7)) * 8;
        union { unsigned short us[8]; uint4 q; } g_;
        #pragma unroll
        for (int j = 0; j < 8; ++j) g_.us[j] = tile[kl + j][cl];
        *(uint4*)&dp[p * 8] = g_.q;
    }
}

// ---------------- shared GEMM machinery ------------------------------------
// 4 waves (2x2), wave tile 64x32, block 128x64, BK=64.
// XOR-swizzled bf16 LDS: 16B granule g of row r holds k-granule g^(r&7).
#define MFMA_TILE(AS, BS)                                                              \
    _Pragma("unroll")                                                                  \
    for (int kkj = 0; kkj < 2; ++kkj) {                                                \
        const int j0 = kkj * 4;                                                        \
        bf16x8 af[4], bfr[2];                                                          \
        _Pragma("unroll")                                                              \
        for (int m = 0; m < 4; ++m)                                                    \
            af[m] = *(const bf16x8*)&AS[wm * 64 + m * 16 + lrow][((j0 + lk) ^ (lrow & 7)) * 8]; \
        _Pragma("unroll")                                                              \
        for (int n = 0; n < 2; ++n)                                                    \
            bfr[n] = *(const bf16x8*)&BS[wn * 32 + n * 16 + lrow][((j0 + lk) ^ (lrow & 7)) * 8]; \
        _Pragma("unroll")                                                              \
        for (int m = 0; m < 4; ++m)                                                    \
            _Pragma("unroll")                                                          \
            for (int n = 0; n < 2; ++n)                                                \
                acc[m][n] = __builtin_amdgcn_mfma_f32_16x16x32_bf16(af[m], bfr[n], acc[m][n], 0, 0, 0); \
    }

#define STAGE_A(BUF, KB)                                                               \
    _Pragma("unroll")                                                                  \
    for (int i = 0; i < 4; ++i) gl_lds16(asrc[i] + (KB), &As[BUF][w * 32 + i * 8][0]);

#define STAGE_B(BUF, KS)                                                               \
    _Pragma("unroll")                                                                  \
    for (int i = 0; i < 2; ++i)                                                        \
        gl_lds16(bsrcB + (size_t)(KS) * 4096 + i * 512,                                \
                 &Bs[BUF][0][0] + w * 1024 + i * 512);

#define K_PIPE(NT)                                                                     \
    STAGE_A(0, 0)                                                                      \
    STAGE_B(0, 0)                                                                      \
    __syncthreads();                                                                   \
    int cur = 0;                                                                       \
    _Pragma("unroll")                                                                  \
    for (int kt = 0; kt < (NT); ++kt) {                                                \
        int nxt = cur ^ 1;                                                             \
        if (kt + 1 < (NT)) { STAGE_A(nxt, (kt + 1) * 64) STAGE_B(nxt, kt + 1) }        \
        __builtin_amdgcn_s_setprio(1);                                                 \
        MFMA_TILE(As[cur], Bs[cur])                                                    \
        __builtin_amdgcn_s_setprio(0);                                                 \
        __syncthreads();                                                               \
        cur = nxt;                                                                     \
    }

// ---------------- grouped GEMM1 + fused silu-gate --------------------------
__global__ __launch_bounds__(256, 3) void gemm1_kernel(
    const unsigned short* __restrict__ Ag, const unsigned short* __restrict__ W1t,
    const int* __restrict__ offs, const int* __restrict__ tile_e,
    const int* __restrict__ tile_r, unsigned short* __restrict__ act)
{
    const int e = tile_e[blockIdx.y];
    if (e < 0) return;
    const int rbeg = offs[e], rend = offs[e + 1];
    const int ne   = rend - rbeg;
    const int row0 = tile_r[blockIdx.y];
    const int cb   = blockIdx.x;             // 0..15
    const int c0   = cb * 32;                // act col block

    __shared__ unsigned short As[2][128][64];   // 32 KB
    __shared__ unsigned short Bs[2][64][64];    // 16 KB

    const int tid  = threadIdx.x;
    const int lane = tid & 63;
    const int w    = tid >> 6;        // 0..3
    const int wm   = w >> 1, wn = w & 1;
    const int lrow = lane & 15;
    const int lk   = lane >> 4;

    const int r8 = lane >> 3, gr = lane & 7;
    const unsigned short* asrc[4];
    #pragma unroll
    for (int i = 0; i < 4; ++i) {
        int q = rbeg + row0 + w * 32 + i * 8 + r8;
        if (q > rend - 1) q = rend - 1;
        asrc[i] = Ag + (size_t)q * H_ + (gr ^ r8) * 8;
    }

    const unsigned short* bsrcB =
        W1t + ((size_t)(e * 16 + cb) * 16) * 4096 + w * 1024 + lane * 8;

    f32x4 acc[4][2];
    #pragma unroll
    for (int m = 0; m < 4; ++m)
        #pragma unroll
        for (int n = 0; n < 2; ++n)
            acc[m][n] = f32x4{0.f, 0.f, 0.f, 0.f};

    K_PIPE(16)

    for (int m = 0; m < 4; ++m) {
        #pragma unroll
        for (int reg = 0; reg < 4; ++reg) {
            int rloc = wm * 64 + m * 16 + lk * 4 + reg;
            if (row0 + rloc < ne) {
                int q = rbeg + row0 + rloc;
                float g = acc[m][0][reg], u = acc[m][1][reg];
                float a = g / (1.f + __expf(-g)) * u;
                act[(size_t)q * I_ + c0 + wn * 16 + lrow] = f2bf(a);
            }
        }
    }
}

// ---------------- grouped GEMM2 -> per-pair partials (no atomics) ----------
__global__ __launch_bounds__(256, 3) void gemm2_kernel(
    const unsigned short* __restrict__ Agact, const unsigned short* __restrict__ W2t,
    const int* __restrict__ offs, const int* __restrict__ tile_e,
    const int* __restrict__ tile_r, const float* __restrict__ pair_w,
    float* __restrict__ C2)
{
    const int e = tile_e[blockIdx.y];
    if (e < 0) return;
    const int rbeg = offs[e], rend = offs[e + 1];
    const int ne   = rend - rbeg;
    const int row0 = tile_r[blockIdx.y];
    const int hb   = blockIdx.x;             // 0..15
    const int c0   = hb * 64;

    __shared__ unsigned short As[2][128][64];
    __shared__ unsigned short Bs[2][64][64];

    const int tid  = threadIdx.x;
    const int lane = tid & 63;
    const int w    = tid >> 6;
    const int wm   = w >> 1, wn = w & 1;
    const int lrow = lane & 15;
    const int lk   = lane >> 4;

    const int r8 = lane >> 3, gr = lane & 7;
    const unsigned short* asrc[4];
    #pragma unroll
    for (int i = 0; i < 4; ++i) {
        int q = rbeg + row0 + w * 32 + i * 8 + r8;
        if (q > rend - 1) q = rend - 1;
        asrc[i] = Agact + (size_t)q * I_ + (gr ^ r8) * 8;
    }

    const unsigned short* bsrcB =
        W2t + ((size_t)(e * 16 + hb) * 8) * 4096 + w * 1024 + lane * 8;

    f32x4 acc[4][2];
    #pragma unroll
    for (int m = 0; m < 4; ++m)
        #pragma unroll
        for (int n = 0; n < 2; ++n)
            acc[m][n] = f32x4{0.f, 0.f, 0.f, 0.f};

    K_PIPE(8)

    for (int m = 0; m < 4; ++m) {
        #pragma unroll
        for (int reg = 0; reg < 4; ++reg) {
            int rloc = wm * 64 + m * 16 + lk * 4 + reg;
            if (row0 + rloc < ne) {
                int q   = rbeg + row0 + rloc;
                float wt = pair_w[q];
                #pragma unroll
                for (int n = 0; n < 2; ++n) {
                    int cg = c0 + wn * 32 + n * 16 + lrow;
                    C2[(size_t)q * H_ + cg] = wt * acc[m][n][reg];
                }
            }
        }
    }
}

// ---------------- combine: out[t] = C2[inv[2t]] + C2[inv[2t+1]] ------------
__global__ __launch_bounds__(256) void combine_kernel(
    const float* __restrict__ C2, const int* __restrict__ inv,
    float* __restrict__ out)
{
    const int t = blockIdx.x;
    const int c = threadIdx.x * 4;
    const int q0 = inv[2 * t], q1 = inv[2 * t + 1];
    const float4 a = *(const float4*)&C2[(size_t)q0 * H_ + c];
    const float4 b = *(const float4*)&C2[(size_t)q1 * H_ + c];
    float4 o;
    o.x = a.x + b.x; o.y = a.y + b.y; o.z = a.z + b.z; o.w = a.w + b.w;
    *(float4*)&out[(size_t)t * H_ + c] = o;
}

extern "C" void kernel_launch(void* const* d_in, const int* in_sizes, int n_in,
                              void* d_out, int out_size, void* d_ws, size_t ws_size,
                              hipStream_t stream)
{
    const float* X  = (const float*)d_in[0];   // [T,H]
    const float* tw = (const float*)d_in[1];   // [T,K]
    const int*   ti = (const int*)d_in[2];     // [T,K]
    const float* W1 = (const float*)d_in[3];   // [E,H,2I]
    const float* W2 = (const float*)d_in[4];   // [E,I,H]
    float* out = (float*)d_out;                // [T,H] fp32

    char* ws = (char*)d_ws;
    int*   offs    = (int*)(ws);               // 17 ints
    int*   tile_e  = (int*)(ws + 128);
    int*   tile_r  = (int*)(ws + 320);
    int*   pair_ts = (int*)(ws + 1024);
    float* pair_w  = (float*)(ws + 1024 + NPAIR * 4);
    int*   inv     = (int*)(ws + 1024 + NPAIR * 8);
    unsigned short* Ag  = (unsigned short*)(ws + (size_t)(1u << 16));            // 8 MiB
    unsigned short* act = (unsigned short*)(ws + (size_t)(1u << 16) + 8388608);  // 4 MiB
    unsigned short* W1t = (unsigned short*)(ws + (size_t)(1u << 16) + 12582912); // 32 MiB
    unsigned short* W2t = (unsigned short*)(ws + (size_t)(1u << 16) + 46137344); // 16 MiB
    float*          C2  = (float*)(ws + (size_t)(1u << 16) + 62914560);          // 16 MiB

    transform_kernel<<<3072, 256, 0, stream>>>(W1, W2, W1t, W2t);

    route_kernel<<<1, 256, 0, stream>>>(tw, ti, offs, tile_e, tile_r, pair_ts, pair_w, inv);

    gather_kernel<<<NPAIR, 256, 0, stream>>>(X, pair_ts, Ag);

    gemm1_kernel<<<dim3(16, MAXTILE), 256, 0, stream>>>(Ag, W1t, offs, tile_e, tile_r, act);

    gemm2_kernel<<<dim3(16, MAXTILE), 256, 0, stream>>>(act, W2t, offs, tile_e, tile_r, pair_w, C2);

    combine_kernel<<<T_, 256, 0, stream>>>(C2, inv, out);
}

// Round 13
// 84.889 us; speedup vs baseline: 1.0784x; 1.0572x over previous
//
#include <hip/hip_runtime.h>

// MoE experts, 3-kernel pipeline:
//   memset(out) -> prep{W transform (wave-private, no barriers) + route + X->bf16}
//   -> grouped GEMM1+silu -> grouped GEMM2 + weighted atomic combine.
// GEMM staging is pure global_load_lds from L3-resident bf16 packets.
#define E_ 16
#define T_ 2048
#define H_ 1024
#define I_ 512
#define NPAIR 4096             // T*K token-expert pairs
#define BM 128
#define MAXTILE 48             // sum ceil(ne/BM) <= 32 + 16

typedef __bf16 bf16x8 __attribute__((ext_vector_type(8)));
typedef float  f32x4  __attribute__((ext_vector_type(4)));

static __device__ __forceinline__ unsigned short f2bf(float f) {
    __bf16 h = (__bf16)f;                       // RNE
    return __builtin_bit_cast(unsigned short, h);
}

// async global->LDS, 16B/lane; dest wave-uniform base + lane*16 (linear);
// source address is per-lane.
static __device__ __forceinline__ void gl_lds16(const void* g, void* l) {
    __builtin_amdgcn_global_load_lds(
        (const __attribute__((address_space(1))) unsigned int*)g,
        (__attribute__((address_space(3))) unsigned int*)l,
        16, 0, 0);
}

// ---------------- prep: W transform + route + X convert --------------------
// Transform: packet(e,colblk,ks) = 64 rows x 8 granules(16B); granule p of row
// bn holds k = ks*64 + (p^(bn&7))*8 + j of col(bn). Wave-private: wave w owns
// chunk rows [16w,16w+16) = XOR bands {2w,2w+1}; for every col it emits the two
// granules p = band^(bn&7). No block barrier anywhere in the transform path.
// Grid: [0,2048) W1 chunks, [2048,3072) W2 chunks, 3072 route, (3072,3200] X.
__global__ __launch_bounds__(256) void prep_kernel(
    const float* __restrict__ W1, const float* __restrict__ W2,
    const float* __restrict__ X,  const float* __restrict__ tw,
    const int* __restrict__ ti,
    unsigned short* __restrict__ W1t, unsigned short* __restrict__ W2t,
    unsigned short* __restrict__ Agc,
    int* __restrict__ offs, int* __restrict__ tile_e, int* __restrict__ tile_r,
    int* __restrict__ pair_ts, float* __restrict__ pair_w)
{
    __shared__ unsigned short tw_s[4][16][130];   // 16.6 KB; reused by route as hist
    __shared__ int ebase[E_];
    const int tid = threadIdx.x;
    const int bid = blockIdx.x;

    if (bid < 3072) {                     // ---- W transform chunk ----
        const float* src;
        unsigned short* dstO;
        int isW1, ch, ks, e;
        if (bid < 2048) {
            isW1 = 1;
            ch = bid & 7; ks = (bid >> 3) & 15; e = bid >> 7;
            src  = W1 + (size_t)e * (H_ * 2 * I_) + (size_t)(ks * 64) * 1024 + ch * 128;
            dstO = W1t;
        } else {
            int b2 = bid - 2048;
            isW1 = 0;
            ch = b2 & 7; ks = (b2 >> 3) & 7; e = b2 >> 6;
            src  = W2 + (size_t)e * (I_ * H_) + (size_t)(ks * 64) * 1024 + ch * 128;
            dstO = W2t;
        }
        const int w    = tid >> 6;        // wave 0..3: rows 16w..16w+15
        const int lane = tid & 63;

        // load 16 rows x 128 cols fp32 (ILP-8), convert, wave-private LDS strip
        float4 r[8];
        #pragma unroll
        for (int i = 0; i < 8; ++i) {
            int row = 16 * w + i * 2 + (lane >> 5);
            r[i] = *(const float4*)(src + (size_t)row * 1024 + (lane & 31) * 4);
        }
        #pragma unroll
        for (int i = 0; i < 8; ++i) {
            ushort4 u;
            u.x = f2bf(r[i].x); u.y = f2bf(r[i].y); u.z = f2bf(r[i].z); u.w = f2bf(r[i].w);
            *(ushort4*)&tw_s[w][i * 2 + (lane >> 5)][(lane & 31) * 4] = u;
        }
        // pack own bands for cols 2*lane, 2*lane+1 (wave-coherent: lgkm only)
        #pragma unroll
        for (int ci = 0; ci < 2; ++ci) {
            const int cl = 2 * lane + ci;
            const int c  = ch * 128 + cl;
            int bn_; size_t dstoff;
            if (isW1) {
                int half = c >> 9, cc = c & 511;
                int cb = cc >> 5, grp = (cc >> 4) & 1, sub = cc & 15;
                bn_ = grp * 32 + half * 16 + sub;
                dstoff = ((size_t)((e * 16 + cb) * 16 + ks)) * 4096;
            } else {
                int hb = c >> 6; bn_ = c & 63;
                dstoff = ((size_t)((e * 16 + hb) * 8 + ks)) * 4096;
            }
            unsigned short* dp = dstO + dstoff + bn_ * 64;
            #pragma unroll
            for (int s = 0; s < 2; ++s) {
                int band = 2 * w + s;
                int p    = band ^ (bn_ & 7);
                union { unsigned short us[8]; uint4 q; } g_;
                #pragma unroll
                for (int j = 0; j < 8; ++j) g_.us[j] = tw_s[w][s * 8 + j][cl];
                *(uint4*)&dp[p * 8] = g_.q;
            }
        }
    } else if (bid == 3072) {             // ---- route (1 block) ----
        unsigned short (*hist)[E_] = (unsigned short (*)[E_])&tw_s[0][0][0];  // 8 KB
        int e_loc[16];
        unsigned short h[E_];
        for (int e = 0; e < E_; ++e) h[e] = 0;
        for (int i = 0; i < 16; ++i) {
            int p = tid * 16 + i;
            int e = ti[p];
            e_loc[i] = e;
            h[e]++;
        }
        for (int e = 0; e < E_; ++e) hist[tid][e] = h[e];
        __syncthreads();
        if (tid < E_) {
            int e = tid, run = 0;
            for (int t = 0; t < 256; ++t) {
                unsigned short c = hist[t][e];
                hist[t][e] = (unsigned short)run;
                run += c;
            }
            ebase[e] = run;
        }
        __syncthreads();
        if (tid == 0) {
            int run = 0, nt = 0;
            for (int e = 0; e < E_; ++e) {
                int c = ebase[e];
                offs[e] = run; ebase[e] = run;
                for (int r = 0; r < c; r += BM) { tile_e[nt] = e; tile_r[nt] = r; ++nt; }
                run += c;
            }
            offs[E_] = run;
            for (; nt < MAXTILE; ++nt) tile_e[nt] = -1;
        }
        __syncthreads();
        int cur[E_];
        for (int e = 0; e < E_; ++e) cur[e] = ebase[e] + hist[tid][e];
        for (int i = 0; i < 16; ++i) {
            int p = tid * 16 + i;
            int e = e_loc[i];
            int pos = cur[e]++;
            pair_ts[pos] = p;          // t = p>>1
            pair_w[pos]  = tw[p];
        }
    } else {                              // ---- X -> bf16 (token order) ----
        const int rb = (bid - 3073) * 16;
        const int c  = tid * 4;
        #pragma unroll
        for (int i = 0; i < 16; ++i) {
            const float4 x = *(const float4*)&X[(size_t)(rb + i) * H_ + c];
            ushort4 b; b.x = f2bf(x.x); b.y = f2bf(x.y); b.z = f2bf(x.z); b.w = f2bf(x.w);
            *(ushort4*)&Agc[(size_t)(rb + i) * H_ + c] = b;
        }
    }
}

// ---------------- shared GEMM machinery ------------------------------------
// 4 waves (2x2), wave tile 64x32, block 128x64, BK=64.
// XOR-swizzled bf16 LDS: 16B granule g of row r holds k-granule g^(r&7).
#define MFMA_TILE(AS, BS)                                                              \
    _Pragma("unroll")                                                                  \
    for (int kkj = 0; kkj < 2; ++kkj) {                                                \
        const int j0 = kkj * 4;                                                        \
        bf16x8 af[4], bfr[2];                                                          \
        _Pragma("unroll")                                                              \
        for (int m = 0; m < 4; ++m)                                                    \
            af[m] = *(const bf16x8*)&AS[wm * 64 + m * 16 + lrow][((j0 + lk) ^ (lrow & 7)) * 8]; \
        _Pragma("unroll")                                                              \
        for (int n = 0; n < 2; ++n)                                                    \
            bfr[n] = *(const bf16x8*)&BS[wn * 32 + n * 16 + lrow][((j0 + lk) ^ (lrow & 7)) * 8]; \
        _Pragma("unroll")                                                              \
        for (int m = 0; m < 4; ++m)                                                    \
            _Pragma("unroll")                                                          \
            for (int n = 0; n < 2; ++n)                                                \
                acc[m][n] = __builtin_amdgcn_mfma_f32_16x16x32_bf16(af[m], bfr[n], acc[m][n], 0, 0, 0); \
    }

#define STAGE_A(BUF, KB)                                                               \
    _Pragma("unroll")                                                                  \
    for (int i = 0; i < 4; ++i) gl_lds16(asrc[i] + (KB), &As[BUF][w * 32 + i * 8][0]);

#define STAGE_B(BUF, KS)                                                               \
    _Pragma("unroll")                                                                  \
    for (int i = 0; i < 2; ++i)                                                        \
        gl_lds16(bsrcB + (size_t)(KS) * 4096 + i * 512,                                \
                 &Bs[BUF][0][0] + w * 1024 + i * 512);

#define K_PIPE(NT)                                                                     \
    STAGE_A(0, 0)                                                                      \
    STAGE_B(0, 0)                                                                      \
    __syncthreads();                                                                   \
    int cur = 0;                                                                       \
    _Pragma("unroll")                                                                  \
    for (int kt = 0; kt < (NT); ++kt) {                                                \
        int nxt = cur ^ 1;                                                             \
        if (kt + 1 < (NT)) { STAGE_A(nxt, (kt + 1) * 64) STAGE_B(nxt, kt + 1) }        \
        __builtin_amdgcn_s_setprio(1);                                                 \
        MFMA_TILE(As[cur], Bs[cur])                                                    \
        __builtin_amdgcn_s_setprio(0);                                                 \
        __syncthreads();                                                               \
        cur = nxt;                                                                     \
    }

// ---------------- grouped GEMM1 + fused silu-gate --------------------------
__global__ __launch_bounds__(256, 3) void gemm1_kernel(
    const unsigned short* __restrict__ Agc, const unsigned short* __restrict__ W1t,
    const int* __restrict__ offs, const int* __restrict__ tile_e,
    const int* __restrict__ tile_r, const int* __restrict__ pair_ts,
    unsigned short* __restrict__ act)
{
    const int e = tile_e[blockIdx.y];
    if (e < 0) return;
    const int rbeg = offs[e], rend = offs[e + 1];
    const int ne   = rend - rbeg;
    const int row0 = tile_r[blockIdx.y];
    const int cb   = blockIdx.x;             // 0..15
    const int c0   = cb * 32;                // act col block

    __shared__ unsigned short As[2][128][64];   // 32 KB
    __shared__ unsigned short Bs[2][64][64];    // 16 KB

    const int tid  = threadIdx.x;
    const int lane = tid & 63;
    const int w    = tid >> 6;        // 0..3
    const int wm   = w >> 1, wn = w & 1;
    const int lrow = lane & 15;
    const int lk   = lane >> 4;

    // A sources: gathered token rows (Agc is token-ordered), stage-time swizzle
    const int r8 = lane >> 3, gr = lane & 7;
    const unsigned short* asrc[4];
    #pragma unroll
    for (int i = 0; i < 4; ++i) {
        int q = rbeg + row0 + w * 32 + i * 8 + r8;
        if (q > rend - 1) q = rend - 1;
        int tok = pair_ts[q] >> 1;
        asrc[i] = Agc + (size_t)tok * H_ + (gr ^ r8) * 8;
    }

    const unsigned short* bsrcB =
        W1t + ((size_t)(e * 16 + cb) * 16) * 4096 + w * 1024 + lane * 8;

    f32x4 acc[4][2];
    #pragma unroll
    for (int m = 0; m < 4; ++m)
        #pragma unroll
        for (int n = 0; n < 2; ++n)
            acc[m][n] = f32x4{0.f, 0.f, 0.f, 0.f};

    K_PIPE(16)

    for (int m = 0; m < 4; ++m) {
        #pragma unroll
        for (int reg = 0; reg < 4; ++reg) {
            int rloc = wm * 64 + m * 16 + lk * 4 + reg;
            if (row0 + rloc < ne) {
                int q = rbeg + row0 + rloc;
                float g = acc[m][0][reg], u = acc[m][1][reg];
                float a = g / (1.f + __expf(-g)) * u;
                act[(size_t)q * I_ + c0 + wn * 16 + lrow] = f2bf(a);
            }
        }
    }
}

// ---------------- grouped GEMM2 + weighted atomic combine ------------------
__global__ __launch_bounds__(256, 3) void gemm2_kernel(
    const unsigned short* __restrict__ act, const unsigned short* __restrict__ W2t,
    const int* __restrict__ offs, const int* __restrict__ tile_e,
    const int* __restrict__ tile_r, const int* __restrict__ pair_ts,
    const float* __restrict__ pair_w, float* __restrict__ out)
{
    const int e = tile_e[blockIdx.y];
    if (e < 0) return;
    const int rbeg = offs[e], rend = offs[e + 1];
    const int ne   = rend - rbeg;
    const int row0 = tile_r[blockIdx.y];
    const int hb   = blockIdx.x;             // 0..15
    const int c0   = hb * 64;

    __shared__ unsigned short As[2][128][64];
    __shared__ unsigned short Bs[2][64][64];

    const int tid  = threadIdx.x;
    const int lane = tid & 63;
    const int w    = tid >> 6;
    const int wm   = w >> 1, wn = w & 1;
    const int lrow = lane & 15;
    const int lk   = lane >> 4;

    const int r8 = lane >> 3, gr = lane & 7;
    const unsigned short* asrc[4];
    #pragma unroll
    for (int i = 0; i < 4; ++i) {
        int q = rbeg + row0 + w * 32 + i * 8 + r8;
        if (q > rend - 1) q = rend - 1;
        asrc[i] = act + (size_t)q * I_ + (gr ^ r8) * 8;
    }

    const unsigned short* bsrcB =
        W2t + ((size_t)(e * 16 + hb) * 8) * 4096 + w * 1024 + lane * 8;

    f32x4 acc[4][2];
    #pragma unroll
    for (int m = 0; m < 4; ++m)
        #pragma unroll
        for (int n = 0; n < 2; ++n)
            acc[m][n] = f32x4{0.f, 0.f, 0.f, 0.f};

    K_PIPE(8)

    for (int m = 0; m < 4; ++m) {
        #pragma unroll
        for (int reg = 0; reg < 4; ++reg) {
            int rloc = wm * 64 + m * 16 + lk * 4 + reg;
            if (row0 + rloc < ne) {
                int q   = rbeg + row0 + rloc;
                int tok = pair_ts[q] >> 1;
                float wt = pair_w[q];
                #pragma unroll
                for (int n = 0; n < 2; ++n) {
                    int cg = c0 + wn * 32 + n * 16 + lrow;
                    atomicAdd(&out[(size_t)tok * H_ + cg], wt * acc[m][n][reg]);
                }
            }
        }
    }
}

extern "C" void kernel_launch(void* const* d_in, const int* in_sizes, int n_in,
                              void* d_out, int out_size, void* d_ws, size_t ws_size,
                              hipStream_t stream)
{
    const float* X  = (const float*)d_in[0];   // [T,H]
    const float* tw = (const float*)d_in[1];   // [T,K]
    const int*   ti = (const int*)d_in[2];     // [T,K]
    const float* W1 = (const float*)d_in[3];   // [E,H,2I]
    const float* W2 = (const float*)d_in[4];   // [E,I,H]
    float* out = (float*)d_out;                // [T,H] fp32

    char* ws = (char*)d_ws;
    int*   offs    = (int*)(ws);               // 17 ints
    int*   tile_e  = (int*)(ws + 128);
    int*   tile_r  = (int*)(ws + 320);
    int*   pair_ts = (int*)(ws + 1024);
    float* pair_w  = (float*)(ws + 1024 + NPAIR * 4);
    unsigned short* Agc = (unsigned short*)(ws + (size_t)(1u << 16));            // 4 MiB
    unsigned short* act = (unsigned short*)(ws + (size_t)(1u << 16) + 4194304);  // 4 MiB
    unsigned short* W1t = (unsigned short*)(ws + (size_t)(1u << 16) + 8388608);  // 32 MiB
    unsigned short* W2t = (unsigned short*)(ws + (size_t)(1u << 16) + 41943040); // 16 MiB

    hipMemsetAsync(d_out, 0, (size_t)out_size * sizeof(float), stream);

    prep_kernel<<<3201, 256, 0, stream>>>(W1, W2, X, tw, ti, W1t, W2t, Agc,
                                          offs, tile_e, tile_r, pair_ts, pair_w);

    gemm1_kernel<<<dim3(16, MAXTILE), 256, 0, stream>>>(Agc, W1t, offs, tile_e, tile_r, pair_ts, act);

    gemm2_kernel<<<dim3(16, MAXTILE), 256, 0, stream>>>(act, W2t, offs, tile_e, tile_r, pair_ts, pair_w, out);
}